// Round 5
// baseline (753.157 us; speedup 1.0000x reference)
//
#include <hip/hip_runtime.h>
#include <cstddef>

#define BB   16384
#define TT_  100
#define FF   64
#define K4   20
#define NOUT 3

typedef float ZBUF[8][8][28];   // [t-in-chunk][g][k + pad->28] ; 28 stride: 2-way banks, 16B-aligned rows

__device__ __forceinline__ float sigf(float x) {
    return __builtin_amdgcn_rcpf(1.0f + __expf(-x));
}
__device__ __forceinline__ float tanhf_fast(float x) {
    return 1.0f - 2.0f * __builtin_amdgcn_rcpf(__expf(2.0f * x) + 1.0f);
}
template <int IMM>
__device__ __forceinline__ float swz(float v) {
    return __int_as_float(__builtin_amdgcn_ds_swizzle(__float_as_int(v), IMM));
}

// Recurrence over NT timesteps (round-3 structure: swizzle h-broadcast, no hist).
template <int NT>
__device__ __forceinline__ void rec_steps(
    ZBUF& zbuf, int g, int ue,
    const float (&u1w)[4][5], const float (&w2w)[4][5], const float (&u2w)[4][5],
    const float (&w3w)[4][5], const float (&u3w)[4][5],
    const float (&bb1)[4], const float (&bb2)[4], const float (&bb3)[4],
    float (&h1)[5], float (&h2)[5], float (&h3)[5],
    float &c1, float &c2, float &c3)
{
#pragma unroll
    for (int s = 0; s < NT; ++s) {
        float z[4];
#pragma unroll
        for (int j = 0; j < 4; ++j) {
            float acc = zbuf[s][g][j * 5 + ue] + bb1[j];
#pragma unroll
            for (int d = 0; d < 5; ++d) acc = fmaf(h1[d], u1w[j][d], acc);
            z[j] = acc;
        }
        {
            const float iv = sigf(z[0]), fv = sigf(z[1]);
            const float gv = tanhf_fast(z[2]), ov = sigf(z[3]);
            c1 = fmaf(fv, c1, iv * gv);
            const float ho = ov * tanhf_fast(c1);
            h1[0] = swz<0x018>(ho); h1[1] = swz<0x038>(ho);
            h1[2] = swz<0x058>(ho); h1[3] = swz<0x078>(ho);
            h1[4] = swz<0x098>(ho);
        }
#pragma unroll
        for (int j = 0; j < 4; ++j) {
            float acc = bb2[j];
#pragma unroll
            for (int d = 0; d < 5; ++d) acc = fmaf(h1[d], w2w[j][d], acc);
#pragma unroll
            for (int d = 0; d < 5; ++d) acc = fmaf(h2[d], u2w[j][d], acc);
            z[j] = acc;
        }
        {
            const float iv = sigf(z[0]), fv = sigf(z[1]);
            const float gv = tanhf_fast(z[2]), ov = sigf(z[3]);
            c2 = fmaf(fv, c2, iv * gv);
            const float ho = ov * tanhf_fast(c2);
            h2[0] = swz<0x018>(ho); h2[1] = swz<0x038>(ho);
            h2[2] = swz<0x058>(ho); h2[3] = swz<0x078>(ho);
            h2[4] = swz<0x098>(ho);
        }
#pragma unroll
        for (int j = 0; j < 4; ++j) {
            float acc = bb3[j];
#pragma unroll
            for (int d = 0; d < 5; ++d) acc = fmaf(h2[d], w3w[j][d], acc);
#pragma unroll
            for (int d = 0; d < 5; ++d) acc = fmaf(h3[d], u3w[j][d], acc);
            z[j] = acc;
        }
        {
            const float iv = sigf(z[0]), fv = sigf(z[1]);
            const float gv = tanhf_fast(z[2]), ov = sigf(z[3]);
            c3 = fmaf(fv, c3, iv * gv);
            const float ho = ov * tanhf_fast(c3);
            h3[0] = swz<0x018>(ho); h3[1] = swz<0x038>(ho);
            h3[2] = swz<0x058>(ho); h3[3] = swz<0x078>(ho);
            h3[4] = swz<0x098>(ho);
        }
    }
}

// Prep: 13 per-chunk copies of W1^T (20x64) into workspace.  Copies (rather
// than one) stop the compiler hoisting the uniform W loads out of the chunk
// loop into impossible SGPR/VGPR pressure.  66.6 KB, L2-hot.
__global__ void prep_w1t(const float* __restrict__ W1, float* __restrict__ W1T) {
    int i = blockIdx.x * 256 + threadIdx.x;
    if (i < 13 * 1280) {
        int j = i % 1280;
        int k = j / 64, f = j % 64;
        W1T[i] = W1[f * K4 + k];
    }
}

// ---------------------------------------------------------------------------
// Fused x-proj + 3-layer LSTM + head.  One wave per 8 batch elements.
// Proj phase: lane = (g, tq) owns one full (b,t) row; W1^T read via
// WAVE-UNIFORM scalar loads (s_load + v_fma v,s,v) -> zero LDS traffic for W
// (round-3/4 spent ~240 LDS-cyc/wave-t on broadcast ds_read_b128 of W1).
// z written to LDS as 5 ds_write_b128.  Rec phase: lane = (g, u), swizzle
// h-broadcast.  x loads for chunk c+1 issued before rec of chunk c (latency
// hidden behind ~2000 cyc of recurrence).
// ---------------------------------------------------------------------------
__global__ __launch_bounds__(64) __attribute__((amdgpu_waves_per_eu(2, 2)))
void fused_lstm_kernel(
    const float* __restrict__ x,
    const float* __restrict__ W1T,  // 13 copies of [K4][FF] in ws
    const float* __restrict__ U1, const float* __restrict__ b1,
    const float* __restrict__ W2, const float* __restrict__ U2, const float* __restrict__ b2,
    const float* __restrict__ W3, const float* __restrict__ U3, const float* __restrict__ b3,
    const float* __restrict__ Wd, const float* __restrict__ bd,
    float* __restrict__ out)
{
    __shared__ ZBUF zbuf;

    const int lane = threadIdx.x;
    const int g    = lane >> 3;        // batch-in-block (same bits in both phases)
    const int u    = lane & 7;
    const int ue   = (u < 5) ? u : 4;
    const int tq   = lane & 7;         // proj-phase timestep-in-chunk
    const int b    = blockIdx.x * 8 + g;

    // ---- chunk-0 x row loads first (hide HBM latency behind setup)
    float4 xa[16];
    {
        const float* xp = x + ((size_t)b * TT_ + tq) * FF;
#pragma unroll
        for (int fc = 0; fc < 16; ++fc) xa[fc] = ((const float4*)xp)[fc];
    }

    // ---- per-lane recurrent weight columns (k = j*5 + ue)
    float u1w[4][5], w2w[4][5], u2w[4][5], w3w[4][5], u3w[4][5];
    float bb1[4], bb2[4], bb3[4];
#pragma unroll
    for (int j = 0; j < 4; ++j) {
        const int k = j * 5 + ue;
#pragma unroll
        for (int d = 0; d < 5; ++d) {
            u1w[j][d] = U1[d * K4 + k];
            w2w[j][d] = W2[d * K4 + k];
            u2w[j][d] = U2[d * K4 + k];
            w3w[j][d] = W3[d * K4 + k];
            u3w[j][d] = U3[d * K4 + k];
        }
        bb1[j] = b1[k];
        bb2[j] = b2[k];
        bb3[j] = b3[k];
    }
    const int uo = (u < NOUT) ? u : 0;
    float wdw[5];
    const float bdw = bd[uo];
#pragma unroll
    for (int d = 0; d < 5; ++d) wdw[d] = Wd[d * NOUT + uo];

    float h1[5] = {0,0,0,0,0}, h2[5] = {0,0,0,0,0}, h3[5] = {0,0,0,0,0};
    float c1 = 0.f, c2 = 0.f, c3 = 0.f;

#pragma unroll 1
    for (int c = 0; c < 13; ++c) {
        // ============ projection: full 64-dot per lane, W wave-uniform =====
        const float* Wc = W1T + c * 1280;   // per-chunk copy (blocks hoisting)
#pragma unroll
        for (int kq = 0; kq < 5; ++kq) {
            float acc[4];
#pragma unroll
            for (int i = 0; i < 4; ++i) acc[i] = b1[kq * 4 + i];  // uniform (re-added? no: bb folded in rec too)
            // NOTE: bias added both here and in rec would double it; zero here:
#pragma unroll
            for (int i = 0; i < 4; ++i) acc[i] = 0.f;
#pragma unroll
            for (int fc = 0; fc < 16; ++fc) {
                const float4 xv = xa[fc];
#pragma unroll
                for (int i = 0; i < 4; ++i) {
                    const float4 wv = *(const float4*)(Wc + (kq * 4 + i) * FF + fc * 4);
                    acc[i] = fmaf(xv.x, wv.x,
                             fmaf(xv.y, wv.y,
                             fmaf(xv.z, wv.z,
                             fmaf(xv.w, wv.w, acc[i]))));
                }
            }
            *(float4*)&zbuf[tq][g][kq * 4] =
                make_float4(acc[0], acc[1], acc[2], acc[3]);   // ds_write_b128
        }

        // ---- issue next chunk's x loads (xa dead after proj; lands in rec)
        if (c < 12) {
            int tn = (c + 1) * 8 + tq;
            if (tn > TT_ - 1) tn = TT_ - 1;       // tail clamp (values unused)
            const float* xp = x + ((size_t)b * TT_ + tn) * FF;
#pragma unroll
            for (int fc = 0; fc < 16; ++fc) xa[fc] = ((const float4*)xp)[fc];
        }

        // ============ recurrence ==========================================
        if (c < 12) {
            rec_steps<8>(zbuf, g, ue, u1w, w2w, u2w, w3w, u3w,
                         bb1, bb2, bb3, h1, h2, h3, c1, c2, c3);
        } else {
            rec_steps<4>(zbuf, g, ue, u1w, w2w, u2w, w3w, u3w,
                         bb1, bb2, bb3, h1, h2, h3, c1, c2, c3);
        }
    }

    // ---- output head
    if (u < NOUT) {
        float sacc = bdw;
#pragma unroll
        for (int d = 0; d < 5; ++d) sacc = fmaf(h3[d], wdw[d], sacc);
        out[b * NOUT + u] = sacc;
    }
}

extern "C" void kernel_launch(void* const* d_in, const int* in_sizes, int n_in,
                              void* d_out, int out_size, void* d_ws, size_t ws_size,
                              hipStream_t stream) {
    const float* x   = (const float*)d_in[0];
    const float* W1  = (const float*)d_in[1];
    const float* U1  = (const float*)d_in[2];
    const float* b1  = (const float*)d_in[3];
    const float* W2  = (const float*)d_in[4];
    const float* U2  = (const float*)d_in[5];
    const float* b2  = (const float*)d_in[6];
    const float* W3  = (const float*)d_in[7];
    const float* U3  = (const float*)d_in[8];
    const float* b3  = (const float*)d_in[9];
    const float* Wd  = (const float*)d_in[10];
    const float* bdp = (const float*)d_in[11];
    float* out = (float*)d_out;
    float* W1T = (float*)d_ws;   // 13 * 1280 floats = 66.6 KB

    prep_w1t<<<(13 * 1280 + 255) / 256, 256, 0, stream>>>(W1, W1T);
    fused_lstm_kernel<<<BB / 8, 64, 0, stream>>>(
        x, W1T, U1, b1, W2, U2, b2, W3, U3, b3, Wd, bdp, out);
}

// Round 6
// 627.540 us; speedup vs baseline: 1.2002x; 1.2002x over previous
//
#include <hip/hip_runtime.h>
#include <cstddef>

#define BB   16384
#define TT_  100
#define FF   64
#define K4   20
#define NOUT 3

__device__ __forceinline__ float sigf(float x) {
    // 1/(1+e^-x); rcp ~1ulp, fine vs 5.9e-4 threshold
    return __builtin_amdgcn_rcpf(1.0f + __expf(-x));
}
__device__ __forceinline__ float tanhf_fast(float x) {
    // tanh(x) = 1 - 2/(e^{2x}+1); safe at +/-inf
    return 1.0f - 2.0f * __builtin_amdgcn_rcpf(__expf(2.0f * x) + 1.0f);
}
template <int IMM>
__device__ __forceinline__ float swz(float v) {
    return __int_as_float(__builtin_amdgcn_ds_swizzle(__float_as_int(v), IMM));
}

// Recurrence over NT timesteps (state passed by ref, fully inlined/unrolled).
template <int NT>
__device__ __forceinline__ void rec_steps(
    float (&zbuf)[8][K4][9], int g, int ue,
    const float (&u1w)[4][5], const float (&w2w)[4][5], const float (&u2w)[4][5],
    const float (&w3w)[4][5], const float (&u3w)[4][5],
    const float (&bb1)[4], const float (&bb2)[4], const float (&bb3)[4],
    float (&h1)[5], float (&h2)[5], float (&h3)[5],
    float &c1, float &c2, float &c3)
{
#pragma unroll
    for (int s = 0; s < NT; ++s) {
        float z[4];
        // ---- layer 1: z = xW1 + b1 + h1@U1
#pragma unroll
        for (int j = 0; j < 4; ++j) {
            float acc = zbuf[s][j * 5 + ue][g] + bb1[j];
#pragma unroll
            for (int d = 0; d < 5; ++d) acc = fmaf(h1[d], u1w[j][d], acc);
            z[j] = acc;
        }
        {
            const float iv = sigf(z[0]), fv = sigf(z[1]);
            const float gv = tanhf_fast(z[2]), ov = sigf(z[3]);
            c1 = fmaf(fv, c1, iv * gv);
            const float ho = ov * tanhf_fast(c1);
            h1[0] = swz<0x018>(ho); h1[1] = swz<0x038>(ho);
            h1[2] = swz<0x058>(ho); h1[3] = swz<0x078>(ho);
            h1[4] = swz<0x098>(ho);
        }
        // ---- layer 2
#pragma unroll
        for (int j = 0; j < 4; ++j) {
            float acc = bb2[j];
#pragma unroll
            for (int d = 0; d < 5; ++d) acc = fmaf(h1[d], w2w[j][d], acc);
#pragma unroll
            for (int d = 0; d < 5; ++d) acc = fmaf(h2[d], u2w[j][d], acc);
            z[j] = acc;
        }
        {
            const float iv = sigf(z[0]), fv = sigf(z[1]);
            const float gv = tanhf_fast(z[2]), ov = sigf(z[3]);
            c2 = fmaf(fv, c2, iv * gv);
            const float ho = ov * tanhf_fast(c2);
            h2[0] = swz<0x018>(ho); h2[1] = swz<0x038>(ho);
            h2[2] = swz<0x058>(ho); h2[3] = swz<0x078>(ho);
            h2[4] = swz<0x098>(ho);
        }
        // ---- layer 3
#pragma unroll
        for (int j = 0; j < 4; ++j) {
            float acc = bb3[j];
#pragma unroll
            for (int d = 0; d < 5; ++d) acc = fmaf(h2[d], w3w[j][d], acc);
#pragma unroll
            for (int d = 0; d < 5; ++d) acc = fmaf(h3[d], u3w[j][d], acc);
            z[j] = acc;
        }
        {
            const float iv = sigf(z[0]), fv = sigf(z[1]);
            const float gv = tanhf_fast(z[2]), ov = sigf(z[3]);
            c3 = fmaf(fv, c3, iv * gv);
            const float ho = ov * tanhf_fast(c3);
            h3[0] = swz<0x018>(ho); h3[1] = swz<0x038>(ho);
            h3[2] = swz<0x058>(ho); h3[3] = swz<0x078>(ho);
            h3[4] = swz<0x098>(ho);
        }
    }
}

// ---------------------------------------------------------------------------
// Fused x-proj + 3-layer LSTM + head (round-3 structure).  One wave per 8
// batch elements.  Chunk = 8 timesteps: proj lanes (g,tq,fh) each own 2 rows,
// k-outer loop reads each W1 float4 once (2-addr LDS broadcast, free) feeding
// 8 FMAs.  Recurrence lanes (g,u): lane u owns unit u's i/f/g/o; h broadcast
// via static ds_swizzle.
//
// ROUND-6 DELTA: amdgpu_waves_per_eu(1,2).  Rounds 2/5 proved the allocator
// pins VGPR_Count=128 under a min-2-waves constraint and spills ~200 MB of
// scratch per call (WRITE_SIZE evidence).  min=1 lifts the budget to 512;
// expected allocation ~190-230 regs -> still >=2 waves/SIMD (grid needs
// exactly 2), spills gone.
// ---------------------------------------------------------------------------
__global__ __launch_bounds__(64) __attribute__((amdgpu_waves_per_eu(1, 2)))
void fused_lstm_kernel(
    const float* __restrict__ x,
    const float* __restrict__ W1, const float* __restrict__ U1, const float* __restrict__ b1,
    const float* __restrict__ W2, const float* __restrict__ U2, const float* __restrict__ b2,
    const float* __restrict__ W3, const float* __restrict__ U3, const float* __restrict__ b3,
    const float* __restrict__ Wd, const float* __restrict__ bd,
    float* __restrict__ out)
{
    __shared__ float sWT[K4][FF];      // W1^T
    __shared__ float zbuf[8][K4][9];   // [t-in-chunk][k][g+pad]

    const int lane = threadIdx.x;
    const int g    = lane >> 3;        // batch-in-block 0..7
    const int u    = lane & 7;         // unit lane (5 active + 3 dup)
    const int ue   = (u < 5) ? u : 4;
    const int tq   = (lane >> 1) & 3;  // proj timestep-quarter
    const int fh   = lane & 1;         // proj f-half
    const int b    = blockIdx.x * 8 + g;

    // ---- chunk-0 x loads first (hide HBM latency behind setup)
    const float* xp0 = x + ((size_t)b * TT_ + tq) * FF + fh * 32;
    const float* xp1 = xp0 + 4 * FF;
    float4 xa0[8], xa1[8];
#pragma unroll
    for (int fc = 0; fc < 8; ++fc) xa0[fc] = ((const float4*)xp0)[fc];
#pragma unroll
    for (int fc = 0; fc < 8; ++fc) xa1[fc] = ((const float4*)xp1)[fc];

    // ---- stage W1^T into LDS
#pragma unroll
    for (int w = 0; w < 20; ++w) {
        int i = w * 64 + lane;
        sWT[i % K4][i / K4] = W1[i];
    }

    // ---- per-lane recurrent weight columns (k = j*5 + ue)
    float u1w[4][5], w2w[4][5], u2w[4][5], w3w[4][5], u3w[4][5];
    float bb1[4], bb2[4], bb3[4];
#pragma unroll
    for (int j = 0; j < 4; ++j) {
        const int k = j * 5 + ue;
#pragma unroll
        for (int d = 0; d < 5; ++d) {
            u1w[j][d] = U1[d * K4 + k];
            w2w[j][d] = W2[d * K4 + k];
            u2w[j][d] = U2[d * K4 + k];
            w3w[j][d] = W3[d * K4 + k];
            u3w[j][d] = U3[d * K4 + k];
        }
        bb1[j] = b1[k];
        bb2[j] = b2[k];
        bb3[j] = b3[k];
    }
    const int uo = (u < NOUT) ? u : 0;
    float wdw[5];
    const float bdw = bd[uo];
#pragma unroll
    for (int d = 0; d < 5; ++d) wdw[d] = Wd[d * NOUT + uo];

    float h1[5] = {0,0,0,0,0}, h2[5] = {0,0,0,0,0}, h3[5] = {0,0,0,0,0};
    float c1 = 0.f, c2 = 0.f, c3 = 0.f;

    const int t1 = tq + (fh << 2);     // zbuf slot this lane writes

    for (int c = 0; c < 13; ++c) {     // 12 full chunks of 8t + tail of 4t
        // ============ projection: k-outer, each W float4 read once ========
#pragma unroll 4
        for (int k = 0; k < K4; ++k) {
            float a0 = 0.f, a1 = 0.f;
#pragma unroll
            for (int fc = 0; fc < 8; ++fc) {
                const float4 wv = *(const float4*)&sWT[k][fh * 32 + fc * 4];
                const float4 x0 = xa0[fc];
                const float4 x1 = xa1[fc];
                a0 = fmaf(x0.x, wv.x, fmaf(x0.y, wv.y, fmaf(x0.z, wv.z, fmaf(x0.w, wv.w, a0))));
                a1 = fmaf(x1.x, wv.x, fmaf(x1.y, wv.y, fmaf(x1.z, wv.z, fmaf(x1.w, wv.w, a1))));
            }
            a0 += swz<0x041F>(a0);     // combine f-halves (xor-1 butterfly)
            a1 += swz<0x041F>(a1);
            zbuf[t1][k][g] = fh ? a1 : a0;
        }

        // ---- prefetch next chunk (lands during recurrence)
        if (c < 12) {
            xp0 += 8 * FF;
            xp1 = (c == 11) ? xp0 : (xp1 + 8 * FF);  // tail: clamp (rows 100+ OOB)
#pragma unroll
            for (int fc = 0; fc < 8; ++fc) xa0[fc] = ((const float4*)xp0)[fc];
#pragma unroll
            for (int fc = 0; fc < 8; ++fc) xa1[fc] = ((const float4*)xp1)[fc];
        }

        // ============ recurrence ==========================================
        if (c < 12) {
            rec_steps<8>(zbuf, g, ue, u1w, w2w, u2w, w3w, u3w,
                         bb1, bb2, bb3, h1, h2, h3, c1, c2, c3);
        } else {
            rec_steps<4>(zbuf, g, ue, u1w, w2w, u2w, w3w, u3w,
                         bb1, bb2, bb3, h1, h2, h3, c1, c2, c3);
        }
    }

    // ---- output head
    if (u < NOUT) {
        float s = bdw;
#pragma unroll
        for (int d = 0; d < 5; ++d) s = fmaf(h3[d], wdw[d], s);
        out[b * NOUT + u] = s;
    }
}

extern "C" void kernel_launch(void* const* d_in, const int* in_sizes, int n_in,
                              void* d_out, int out_size, void* d_ws, size_t ws_size,
                              hipStream_t stream) {
    const float* x   = (const float*)d_in[0];
    const float* W1  = (const float*)d_in[1];
    const float* U1  = (const float*)d_in[2];
    const float* b1  = (const float*)d_in[3];
    const float* W2  = (const float*)d_in[4];
    const float* U2  = (const float*)d_in[5];
    const float* b2  = (const float*)d_in[6];
    const float* W3  = (const float*)d_in[7];
    const float* U3  = (const float*)d_in[8];
    const float* b3  = (const float*)d_in[9];
    const float* Wd  = (const float*)d_in[10];
    const float* bdp = (const float*)d_in[11];
    float* out = (float*)d_out;

    fused_lstm_kernel<<<BB / 8, 64, 0, stream>>>(
        x, W1, U1, b1, W2, U2, b2, W3, U3, b3, Wd, bdp, out);
}